// Round 1
// baseline (140.779 us; speedup 1.0000x reference)
//
#include <hip/hip_runtime.h>
#include <hip/hip_bf16.h>
#include <math.h>

#define D 256
#define B 512
#define ROWS_PER_BLOCK 2
#define MAX_ITER 80
#define DZ_TOL 2e-6f

// ---------------------------------------------------------------------------
// Tiled transpose: WT[j*D + i] = W[i*D + j]  (so the Picard kernel's inner
// loads are lane-consecutive / coalesced).
// grid (8,8), block (32,8)
// ---------------------------------------------------------------------------
__global__ void transpose_256(const float* __restrict__ W, float* __restrict__ WT) {
    __shared__ float tile[32][33];
    int bx = blockIdx.x * 32;   // col block in W
    int by = blockIdx.y * 32;   // row block in W
    int tx = threadIdx.x, ty = threadIdx.y;

    // load 32x32 tile of W (coalesced along rows)
    #pragma unroll
    for (int k = 0; k < 32; k += 8) {
        tile[ty + k][tx] = W[(by + ty + k) * D + (bx + tx)];
    }
    __syncthreads();
    // write transposed (coalesced along rows of WT)
    #pragma unroll
    for (int k = 0; k < 32; k += 8) {
        WT[(bx + ty + k) * D + (by + tx)] = tile[tx][ty + k];
    }
}

// ---------------------------------------------------------------------------
// Picard fixed-point iteration: z <- tanh(W z + x), 2 rows per block.
// Thread i owns element i of both rows. z pair lives in LDS as float2
// (uniform-address broadcast per j -> conflict-free).
// At convergence the required output tanh(W z + x) equals z itself.
// ---------------------------------------------------------------------------
__global__ __launch_bounds__(256) void picard_256(const float* __restrict__ x,
                                                  const float* __restrict__ WT,
                                                  float* __restrict__ out) {
    const int tid  = threadIdx.x;
    const int row0 = blockIdx.x * ROWS_PER_BLOCK;

    __shared__ float2 zsh[D];
    __shared__ int s_flag;

    const float x0 = x[(row0 + 0) * D + tid];
    const float x1 = x[(row0 + 1) * D + tid];

    float z0 = tanhf(x0);
    float z1 = tanhf(x1);

    zsh[tid] = make_float2(z0, z1);
    __syncthreads();

    for (int it = 0; it < MAX_ITER; ++it) {
        float acc0 = x0, acc1 = x1;
        const float* wp = WT + tid;           // WT[j*D + tid], coalesced per j
        #pragma unroll 8
        for (int j = 0; j < D; ++j) {
            const float w  = wp[j * D];
            const float2 zz = zsh[j];
            acc0 = fmaf(w, zz.x, acc0);
            acc1 = fmaf(w, zz.y, acc1);
        }
        const float zn0 = tanhf(acc0);
        const float zn1 = tanhf(acc1);
        const float diff = fmaxf(fabsf(zn0 - z0), fabsf(zn1 - z1));
        z0 = zn0; z1 = zn1;

        __syncthreads();                       // all lanes done reading old zsh
        zsh[tid] = make_float2(z0, z1);        // publish new z
        if (tid == 0) s_flag = 0;
        __syncthreads();
        if (diff > DZ_TOL) s_flag = 1;         // benign race (all write 1)
        __syncthreads();
        if (s_flag == 0) break;                // block-uniform exit
    }

    // At the fixed point, tanh(W z + x) == z, so z is the answer.
    out[(row0 + 0) * D + tid] = z0;
    out[(row0 + 1) * D + tid] = z1;
}

extern "C" void kernel_launch(void* const* d_in, const int* in_sizes, int n_in,
                              void* d_out, int out_size, void* d_ws, size_t ws_size,
                              hipStream_t stream) {
    const float* x = (const float*)d_in[0];   // [B, D] f32
    const float* W = (const float*)d_in[1];   // [D, D] f32
    float* out = (float*)d_out;               // [B, D] f32
    float* WT  = (float*)d_ws;                // D*D f32 = 256 KB scratch

    transpose_256<<<dim3(8, 8), dim3(32, 8), 0, stream>>>(W, WT);
    picard_256<<<B / ROWS_PER_BLOCK, 256, 0, stream>>>(x, WT, out);
}

// Round 2
// 86.118 us; speedup vs baseline: 1.6347x; 1.6347x over previous
//
#include <hip/hip_runtime.h>
#include <hip/hip_bf16.h>
#include <hip/hip_fp16.h>
#include <math.h>

#define D 256
#define B 512
#define ITERS 20

typedef _Float16 half2_t __attribute__((ext_vector_type(2)));

// ---------------------------------------------------------------------------
// dot2: acc += w.x*z.x + w.y*z.y  (f16 pairs, f32 accumulate)
// ---------------------------------------------------------------------------
__device__ __forceinline__ float dot2(unsigned int w, unsigned int z, float acc) {
#if __has_builtin(__builtin_amdgcn_fdot2)
    return __builtin_amdgcn_fdot2(__builtin_bit_cast(half2_t, w),
                                  __builtin_bit_cast(half2_t, z), acc, false);
#else
    __half2 wh = __builtin_bit_cast(__half2, w);
    __half2 zh = __builtin_bit_cast(__half2, z);
    float2 wf = __half22float2(wh);
    float2 zf = __half22float2(zh);
    return fmaf(wf.x, zf.x, fmaf(wf.y, zf.y, acc));
#endif
}

// ---------------------------------------------------------------------------
// prep: Wg[j2*256 + i] = pack_f16x2( W[i][2*j2], W[i][2*j2+1] )
// (transposed + f16-packed so picard's W-register loads are lane-coalesced)
// grid (4 j2-tiles, 8 i-tiles), block (64, 4)
// ---------------------------------------------------------------------------
__global__ void prep_pack(const float* __restrict__ W, unsigned int* __restrict__ Wg) {
    __shared__ float tile[32][66];   // [i_loc][j_loc], pad 66 -> 2-way max on reads
    const int jt = blockIdx.x;       // j-tile: j in [jt*64, jt*64+64)
    const int it = blockIdx.y;       // i-tile: i in [it*32, it*32+32)
    const int tx = threadIdx.x;      // 0..63  (j offset)
    const int ty = threadIdx.y;      // 0..3

    #pragma unroll
    for (int k = 0; k < 8; ++k) {
        const int i_loc = ty + 4 * k;
        tile[i_loc][tx] = W[(it * 32 + i_loc) * D + jt * 64 + tx];
    }
    __syncthreads();

    const int t = tx + 64 * ty;      // 0..255
    #pragma unroll
    for (int k = 0; k < 4; ++k) {
        const int o = t + 256 * k;       // 0..1023
        const int j2_loc = o >> 5;       // 0..31
        const int i_loc  = o & 31;       // 0..31
        const float a = tile[i_loc][2 * j2_loc];
        const float b = tile[i_loc][2 * j2_loc + 1];
        const unsigned int lo = __half_as_ushort(__float2half_rn(a));
        const unsigned int hi = __half_as_ushort(__float2half_rn(b));
        Wg[(jt * 32 + j2_loc) * D + it * 32 + i_loc] = (hi << 16) | lo;
    }
}

// ---------------------------------------------------------------------------
// picard: z <- tanh(W z + x), 2 rows per block, W register-resident (f16x2).
// 512 threads = 8 waves. Thread (i = tid&255, h = tid>>8) owns output col i,
// j-half h. z is distributed: lane l of an h-wave holds the f16 pair
// (z[128h+2l], z[128h+2l+1]); v_readlane broadcasts it into the dot loop.
// Output tanh(Wz+x) of the final iteration is the answer itself.
// ---------------------------------------------------------------------------
__global__ __launch_bounds__(512) void picard_reg(const float* __restrict__ x,
                                                  const unsigned int* __restrict__ Wg,
                                                  float* __restrict__ out) {
    const int tid  = threadIdx.x;
    const int i    = tid & 255;
    const int h    = tid >> 8;       // wave-uniform (waves 0-3: h=0, 4-7: h=1)
    const int lane = tid & 63;
    const int row0 = blockIdx.x * 2;

    __shared__ float  part[2][D];    // h=1 partial sums
    __shared__ __half zbuf[2][D];    // z broadcast buffer

    const float x0 = x[row0 * D + i];
    const float x1 = x[row0 * D + D + i];

    // W into registers: w[jj] = pack(W[i][2*(64h+jj)], W[i][2*(64h+jj)+1])
    unsigned int w[64];
    const unsigned int* wp = Wg + (h * 64) * D + i;
    #pragma unroll
    for (int jj = 0; jj < 64; ++jj) w[jj] = wp[jj * D];

    // z0 = tanh(x)
    if (h == 0) {
        zbuf[0][i] = __float2half_rn(tanhf(x0));
        zbuf[1][i] = __float2half_rn(tanhf(x1));
    }
    __syncthreads();
    unsigned int zr0 = *(const unsigned int*)&zbuf[0][2 * (64 * h + lane)];
    unsigned int zr1 = *(const unsigned int*)&zbuf[1][2 * (64 * h + lane)];

    for (int it = 0; it < ITERS; ++it) {
        // ---- dot phase: acc_r = sum over this thread's j-half ----
        float a0 = 0.f, a1 = 0.f, b0 = 0.f, b1 = 0.f;   // 2 chains per row
        #pragma unroll
        for (int jj = 0; jj < 32; ++jj) {
            const unsigned int s0 = (unsigned int)__builtin_amdgcn_readlane((int)zr0, jj);
            const unsigned int s1 = (unsigned int)__builtin_amdgcn_readlane((int)zr1, jj);
            a0 = dot2(w[jj], s0, a0);
            a1 = dot2(w[jj], s1, a1);
            const unsigned int t0 = (unsigned int)__builtin_amdgcn_readlane((int)zr0, jj + 32);
            const unsigned int t1 = (unsigned int)__builtin_amdgcn_readlane((int)zr1, jj + 32);
            b0 = dot2(w[jj + 32], t0, b0);
            b1 = dot2(w[jj + 32], t1, b1);
        }
        const float acc0 = a0 + b0;
        const float acc1 = a1 + b1;

        // ---- reduce across halves + tanh ----
        if (h == 1) { part[0][i] = acc0; part[1][i] = acc1; }
        __syncthreads();
        if (h == 0) {
            const float t0 = tanhf(acc0 + part[0][i] + x0);
            const float t1 = tanhf(acc1 + part[1][i] + x1);
            if (it == ITERS - 1) {
                out[row0 * D + i]     = t0;   // = tanh(W z + x) = final answer
                out[row0 * D + D + i] = t1;
            } else {
                zbuf[0][i] = __float2half_rn(t0);
                zbuf[1][i] = __float2half_rn(t1);
            }
        }
        __syncthreads();
        if (it < ITERS - 1) {
            zr0 = *(const unsigned int*)&zbuf[0][2 * (64 * h + lane)];
            zr1 = *(const unsigned int*)&zbuf[1][2 * (64 * h + lane)];
        }
    }
}

extern "C" void kernel_launch(void* const* d_in, const int* in_sizes, int n_in,
                              void* d_out, int out_size, void* d_ws, size_t ws_size,
                              hipStream_t stream) {
    const float* x = (const float*)d_in[0];       // [B, D] f32
    const float* W = (const float*)d_in[1];       // [D, D] f32
    float* out = (float*)d_out;                   // [B, D] f32
    unsigned int* Wg = (unsigned int*)d_ws;       // [D/2][D] f16x2 = 128 KB

    prep_pack<<<dim3(4, 8), dim3(64, 4), 0, stream>>>(W, Wg);
    picard_reg<<<B / 2, 512, 0, stream>>>(x, Wg, out);
}

// Round 3
// 74.591 us; speedup vs baseline: 1.8873x; 1.1545x over previous
//
#include <hip/hip_runtime.h>
#include <hip/hip_fp16.h>
#include <math.h>

#define D 256
#define B 512
#define RB 16       // batch rows per block
#define ITERS 20

typedef _Float16 f16x8 __attribute__((ext_vector_type(8)));
typedef _Float16 f16x4 __attribute__((ext_vector_type(4)));
typedef float    f32x4 __attribute__((ext_vector_type(4)));

// tanh(v) = 1 - 2/(e^{2v}+1); |v| <= ~7 here so exp2 never overflows.
__device__ __forceinline__ float fast_tanh(float v) {
    float ex = __builtin_amdgcn_exp2f(v * 2.885390081777927f);   // 2*log2(e)
    return fmaf(-2.0f, __builtin_amdgcn_rcpf(ex + 1.0f), 1.0f);
}

// ---------------------------------------------------------------------------
// One block = 16 batch rows, 4 waves (256 thr). Per iter: T = W @ z^T + x^T,
// z <- tanh(T). A-operand (W) is register-resident f16 frags (loaded once
// from f32 W, no prep kernel). z is f16 in LDS, XOR-swizzled both sides.
// C-layout (m89): col = lane&15 -> batch row m; row = (lane>>4)*4+reg -> n.
// Final iteration's tanh(Wz+x) is the answer itself.
// ---------------------------------------------------------------------------
__global__ __launch_bounds__(256) void picard_mfma(const float* __restrict__ x,
                                                   const float* __restrict__ W,
                                                   float* __restrict__ out) {
    const int tid  = threadIdx.x;
    const int lane = tid & 63;
    const int wv   = tid >> 6;       // wave 0..3 -> n-tiles wv*4 .. wv*4+3
    const int c    = lane & 15;      // = batch row m within tile
    const int g    = lane >> 4;      // 0..3
    const int row0 = blockIdx.x * RB;

    __shared__ __align__(16) unsigned short zlds[RB * D];   // f16 z[m][k], swizzled

    // ---- preload W as A-frags: wfrag[nt][ks] -> A[n = (wv*4+nt)*16+c][k = ks*32+g*8+j]
    f16x8 wfrag[4][8];
    #pragma unroll
    for (int nt = 0; nt < 4; ++nt) {
        const float* wr = W + ((wv * 4 + nt) * 16 + c) * D + g * 8;
        #pragma unroll
        for (int ks = 0; ks < 8; ++ks) {
            const float* p = wr + ks * 32;
            f16x8 f;
            #pragma unroll
            for (int j = 0; j < 8; ++j) f[j] = (_Float16)p[j];
            wfrag[nt][ks] = f;
        }
    }

    // ---- x in C-layout: xfrag[nt][r] = x[row0+c][ (wv*4+nt)*16 + g*4 + r ]
    f32x4 xfrag[4];
    #pragma unroll
    for (int nt = 0; nt < 4; ++nt)
        xfrag[nt] = *(const f32x4*)(x + (row0 + c) * D + (wv * 4 + nt) * 16 + g * 4);

    // ---- z0 = tanh(x), write to LDS (swizzled b64: 4 consecutive k per nt)
    #pragma unroll
    for (int nt = 0; nt < 4; ++nt) {
        const int n0 = (wv * 4 + nt) * 16 + g * 4;
        f16x4 h;
        #pragma unroll
        for (int r = 0; r < 4; ++r) h[r] = (_Float16)fast_tanh(xfrag[nt][r]);
        *(f16x4*)((char*)zlds + ((c * 512 + n0 * 2) ^ ((c & 7) << 4))) = h;
    }

    for (int it = 0; it < ITERS; ++it) {
        __syncthreads();   // z writes visible
        // ---- B-frags: B[k][m] = z[m = c][k = ks*32 + g*8 + j], swizzled b128
        f16x8 bf[8];
        #pragma unroll
        for (int ks = 0; ks < 8; ++ks)
            bf[ks] = *(const f16x8*)((const char*)zlds +
                        ((c * 512 + ks * 64 + g * 16) ^ ((c & 7) << 4)));
        __syncthreads();   // all reads done before anyone overwrites z

        // ---- T = W z^T + x^T
        f32x4 acc[4];
        #pragma unroll
        for (int nt = 0; nt < 4; ++nt) {
            acc[nt] = xfrag[nt];
            #pragma unroll
            for (int ks = 0; ks < 8; ++ks)
                acc[nt] = __builtin_amdgcn_mfma_f32_16x16x32_f16(wfrag[nt][ks], bf[ks], acc[nt], 0, 0, 0);
        }

        if (it < ITERS - 1) {
            // ---- z = tanh(T) back to LDS
            #pragma unroll
            for (int nt = 0; nt < 4; ++nt) {
                const int n0 = (wv * 4 + nt) * 16 + g * 4;
                f16x4 h;
                #pragma unroll
                for (int r = 0; r < 4; ++r) h[r] = (_Float16)fast_tanh(acc[nt][r]);
                *(f16x4*)((char*)zlds + ((c * 512 + n0 * 2) ^ ((c & 7) << 4))) = h;
            }
        } else {
            // ---- final: out = tanh(W z + x), f32, dwordx4 (4 lanes share a 64B line)
            #pragma unroll
            for (int nt = 0; nt < 4; ++nt) {
                const int n0 = (wv * 4 + nt) * 16 + g * 4;
                f32x4 o;
                #pragma unroll
                for (int r = 0; r < 4; ++r) o[r] = fast_tanh(acc[nt][r]);
                *(f32x4*)(out + (row0 + c) * D + n0) = o;
            }
        }
    }
}

extern "C" void kernel_launch(void* const* d_in, const int* in_sizes, int n_in,
                              void* d_out, int out_size, void* d_ws, size_t ws_size,
                              hipStream_t stream) {
    const float* x = (const float*)d_in[0];   // [B, D] f32
    const float* W = (const float*)d_in[1];   // [D, D] f32
    float* out = (float*)d_out;               // [B, D] f32
    (void)d_ws; (void)ws_size;

    picard_mfma<<<B / RB, 256, 0, stream>>>(x, W, out);
}

// Round 5
// 70.862 us; speedup vs baseline: 1.9867x; 1.0526x over previous
//
#include <hip/hip_runtime.h>
#include <hip/hip_fp16.h>
#include <math.h>

#define D 256
#define B 512
#define RB 16       // batch rows per block
#define ITERS 20
#define NW 8        // waves per block

typedef _Float16 f16x8 __attribute__((ext_vector_type(8)));
typedef _Float16 f16x4 __attribute__((ext_vector_type(4)));
typedef float    f32x4 __attribute__((ext_vector_type(4)));

// tanh(v) = 1 - 2/(e^{2v}+1); |v| <= ~9 here so exp2 never overflows.
__device__ __forceinline__ float fast_tanh(float v) {
    float ex = __builtin_amdgcn_exp2f(v * 2.885390081777927f);   // 2*log2(e)
    return fmaf(-2.0f, __builtin_amdgcn_rcpf(ex + 1.0f), 1.0f);
}

// ---------------------------------------------------------------------------
// prep: W (f32, row-major) -> Wh (f16, frag-major) so picard's register
// preload is fully coalesced dwordx4.
// Element (i,k): nt=i>>4, c=i&15, ks=k>>5, g=(k>>3)&3, j=k&7, lane=g*16+c;
// Wh[((nt*8+ks)*64+lane)*8 + j] = (f16) W[i][k].
// 8192 threads, each handles one (row i, 8-col chunk k8): coalesced read.
// ---------------------------------------------------------------------------
__global__ __launch_bounds__(256) void prep_fragpack(const float* __restrict__ W,
                                                     _Float16* __restrict__ Wh) {
    const int t  = blockIdx.x * 256 + threadIdx.x;   // 0..8191
    const int i  = t >> 5;                           // row 0..255
    const int k8 = t & 31;                           // 8-col chunk
    const float* p = W + i * D + k8 * 8;
    f16x8 h;
    #pragma unroll
    for (int j = 0; j < 8; ++j) h[j] = (_Float16)p[j];
    const int nt = i >> 4, c = i & 15;
    const int ks = k8 >> 2, g = k8 & 3;
    const int lane = g * 16 + c;
    *(f16x8*)(Wh + ((nt * 8 + ks) * 64 + lane) * 8) = h;
}

// ---------------------------------------------------------------------------
// One block = 16 batch rows, 8 waves (512 thr). Wave wv owns n-tiles
// {2wv, 2wv+1}. Per iter: T = W @ z^T + x^T, z <- tanh(T). W register-
// resident (f16 frags, coalesced preload from Wh). z f16 in LDS, XOR-
// swizzled both sides. C-layout: col=lane&15 -> batch row, row=g*4+r -> n.
// Final iteration's tanh(Wz+x) is the answer itself.
// ---------------------------------------------------------------------------
__global__ __launch_bounds__(512) void picard_mfma(const float* __restrict__ x,
                                                   const _Float16* __restrict__ Wh,
                                                   float* __restrict__ out) {
    const int tid  = threadIdx.x;
    const int lane = tid & 63;
    const int wv   = tid >> 6;       // 0..7
    const int c    = lane & 15;      // batch row within tile
    const int g    = lane >> 4;      // 0..3
    const int row0 = blockIdx.x * RB;

    __shared__ __align__(16) unsigned short zlds[RB * D];   // f16 z[m][k], swizzled

    // ---- W frags: coalesced dwordx4 loads (16B/lane, 1KB/wave/instr)
    f16x8 wfrag[2][8];
    #pragma unroll
    for (int nt = 0; nt < 2; ++nt)
        #pragma unroll
        for (int ks = 0; ks < 8; ++ks)
            wfrag[nt][ks] = *(const f16x8*)(Wh + (((2 * wv + nt) * 8 + ks) * 64 + lane) * 8);

    // ---- x in C-layout: xfrag[nt][r] = x[row0+c][(2wv+nt)*16 + g*4 + r]
    f32x4 xfrag[2];
    #pragma unroll
    for (int nt = 0; nt < 2; ++nt)
        xfrag[nt] = *(const f32x4*)(x + (row0 + c) * D + (2 * wv + nt) * 16 + g * 4);

    // ---- z0 = tanh(x) -> LDS (swizzled f16x4)
    #pragma unroll
    for (int nt = 0; nt < 2; ++nt) {
        const int n0 = (2 * wv + nt) * 16 + g * 4;
        f16x4 h;
        #pragma unroll
        for (int r = 0; r < 4; ++r) h[r] = (_Float16)fast_tanh(xfrag[nt][r]);
        *(f16x4*)((char*)zlds + ((c * 512 + n0 * 2) ^ ((c & 7) << 4))) = h;
    }

    for (int it = 0; it < ITERS; ++it) {
        __syncthreads();   // z writes visible
        // ---- B-frags: B[k][m] = z[m=c][k=ks*32+g*8+j], swizzled b128
        f16x8 bf[8];
        #pragma unroll
        for (int ks = 0; ks < 8; ++ks)
            bf[ks] = *(const f16x8*)((const char*)zlds +
                        ((c * 512 + ks * 64 + g * 16) ^ ((c & 7) << 4)));
        __syncthreads();   // all reads done before anyone overwrites z

        // ---- T = W z^T + x^T
        f32x4 acc[2];
        #pragma unroll
        for (int nt = 0; nt < 2; ++nt) {
            acc[nt] = xfrag[nt];
            #pragma unroll
            for (int ks = 0; ks < 8; ++ks)
                acc[nt] = __builtin_amdgcn_mfma_f32_16x16x32_f16(wfrag[nt][ks], bf[ks], acc[nt], 0, 0, 0);
        }

        if (it < ITERS - 1) {
            // ---- z = tanh(T) back to LDS
            #pragma unroll
            for (int nt = 0; nt < 2; ++nt) {
                const int n0 = (2 * wv + nt) * 16 + g * 4;
                f16x4 h;
                #pragma unroll
                for (int r = 0; r < 4; ++r) h[r] = (_Float16)fast_tanh(acc[nt][r]);
                *(f16x4*)((char*)zlds + ((c * 512 + n0 * 2) ^ ((c & 7) << 4))) = h;
            }
        } else {
            // ---- final: out = tanh(W z + x), f32x4
            #pragma unroll
            for (int nt = 0; nt < 2; ++nt) {
                const int n0 = (2 * wv + nt) * 16 + g * 4;
                f32x4 o;
                #pragma unroll
                for (int r = 0; r < 4; ++r) o[r] = fast_tanh(acc[nt][r]);
                *(f32x4*)(out + (row0 + c) * D + n0) = o;
            }
        }
    }
}

extern "C" void kernel_launch(void* const* d_in, const int* in_sizes, int n_in,
                              void* d_out, int out_size, void* d_ws, size_t ws_size,
                              hipStream_t stream) {
    const float* x = (const float*)d_in[0];   // [B, D] f32
    const float* W = (const float*)d_in[1];   // [D, D] f32
    float* out = (float*)d_out;               // [B, D] f32
    _Float16* Wh = (_Float16*)d_ws;           // 64K f16 = 128 KB frag-major W

    prep_fragpack<<<32, 256, 0, stream>>>(W, Wh);
    picard_mfma<<<B / RB, 512, 0, stream>>>(x, Wh, out);
}

// Round 6
// 64.687 us; speedup vs baseline: 2.1763x; 1.0955x over previous
//
#include <hip/hip_runtime.h>
#include <hip/hip_fp16.h>
#include <math.h>

#define D 256
#define B 512
#define RB 16       // batch rows per block
#define ITERS 12    // contraction ~0.5/iter: err ~1e-3 at 12, below the 0.0039 ref floor

typedef _Float16 f16x8 __attribute__((ext_vector_type(8)));
typedef _Float16 f16x4 __attribute__((ext_vector_type(4)));
typedef float    f32x4 __attribute__((ext_vector_type(4)));

// tanh(v) = 1 - 2/(e^{2v}+1); |v| <= ~9 here so exp2 never overflows.
__device__ __forceinline__ float fast_tanh(float v) {
    float ex = __builtin_amdgcn_exp2f(v * 2.885390081777927f);   // 2*log2(e)
    return fmaf(-2.0f, __builtin_amdgcn_rcpf(ex + 1.0f), 1.0f);
}

// ---------------------------------------------------------------------------
// prep: W (f32, row-major) -> Wh (f16, frag-major) so picard's register
// preload is fully coalesced dwordx4.
// Element (i,k): nt=i>>4, c=i&15, ks=k>>5, g=(k>>3)&3, j=k&7, lane=g*16+c;
// Wh[((nt*8+ks)*64+lane)*8 + j] = (f16) W[i][k].
// ---------------------------------------------------------------------------
__global__ __launch_bounds__(256) void prep_fragpack(const float* __restrict__ W,
                                                     _Float16* __restrict__ Wh) {
    const int t  = blockIdx.x * 256 + threadIdx.x;   // 0..8191
    const int i  = t >> 5;                           // row 0..255
    const int k8 = t & 31;                           // 8-col chunk
    const float* p = W + i * D + k8 * 8;
    f16x8 h;
    #pragma unroll
    for (int j = 0; j < 8; ++j) h[j] = (_Float16)p[j];
    const int nt = i >> 4, c = i & 15;
    const int ks = k8 >> 2, g = k8 & 3;
    const int lane = g * 16 + c;
    *(f16x8*)(Wh + ((nt * 8 + ks) * 64 + lane) * 8) = h;
}

// ---------------------------------------------------------------------------
// One block = 16 batch rows, 8 waves (512 thr). Wave wv owns n-tiles
// {2wv, 2wv+1}. Per iter: T = W @ z^T + x^T, z <- tanh(T). W register-
// resident (f16 frags). z f16 in LDS, XOR-swizzled both sides, PING-PONG
// buffered so each iteration needs only ONE barrier (reads of buf p drain
// at the wave's own syncthreads; writes go to buf p^1).
// C-layout: col=lane&15 -> batch row, row=g*4+r -> n.
// Final iteration's tanh(Wz+x) is the answer itself.
// ---------------------------------------------------------------------------
__global__ __launch_bounds__(512) void picard_mfma(const float* __restrict__ x,
                                                   const _Float16* __restrict__ Wh,
                                                   float* __restrict__ out) {
    const int tid  = threadIdx.x;
    const int lane = tid & 63;
    const int wv   = tid >> 6;       // 0..7
    const int c    = lane & 15;      // batch row within tile
    const int g    = lane >> 4;      // 0..3
    const int row0 = blockIdx.x * RB;

    __shared__ __align__(16) unsigned short zlds[2][RB * D];  // ping-pong f16 z

    // ---- W frags: coalesced dwordx4 loads (16B/lane)
    f16x8 wfrag[2][8];
    #pragma unroll
    for (int nt = 0; nt < 2; ++nt)
        #pragma unroll
        for (int ks = 0; ks < 8; ++ks)
            wfrag[nt][ks] = *(const f16x8*)(Wh + (((2 * wv + nt) * 8 + ks) * 64 + lane) * 8);

    // ---- x in C-layout: xfrag[nt][r] = x[row0+c][(2wv+nt)*16 + g*4 + r]
    f32x4 xfrag[2];
    #pragma unroll
    for (int nt = 0; nt < 2; ++nt)
        xfrag[nt] = *(const f32x4*)(x + (row0 + c) * D + (2 * wv + nt) * 16 + g * 4);

    // ---- z0 = tanh(x) -> zlds[0] (swizzled f16x4)
    #pragma unroll
    for (int nt = 0; nt < 2; ++nt) {
        const int n0 = (2 * wv + nt) * 16 + g * 4;
        f16x4 h;
        #pragma unroll
        for (int r = 0; r < 4; ++r) h[r] = (_Float16)fast_tanh(xfrag[nt][r]);
        *(f16x4*)((char*)zlds[0] + ((c * 512 + n0 * 2) ^ ((c & 7) << 4))) = h;
    }
    __syncthreads();

    #pragma unroll 1
    for (int it = 0; it < ITERS; ++it) {
        const unsigned short* zr = zlds[it & 1];
        unsigned short*       zw = zlds[(it & 1) ^ 1];

        // ---- B-frags: B[k][m] = z[m=c][k=ks*32+g*8+j], swizzled b128
        f16x8 bf[8];
        #pragma unroll
        for (int ks = 0; ks < 8; ++ks)
            bf[ks] = *(const f16x8*)((const char*)zr +
                        ((c * 512 + ks * 64 + g * 16) ^ ((c & 7) << 4)));

        // ---- T = W z^T + x^T
        f32x4 acc[2];
        #pragma unroll
        for (int nt = 0; nt < 2; ++nt) {
            acc[nt] = xfrag[nt];
            #pragma unroll
            for (int ks = 0; ks < 8; ++ks)
                acc[nt] = __builtin_amdgcn_mfma_f32_16x16x32_f16(wfrag[nt][ks], bf[ks], acc[nt], 0, 0, 0);
        }

        if (it < ITERS - 1) {
            // ---- z = tanh(T) into the other buffer
            #pragma unroll
            for (int nt = 0; nt < 2; ++nt) {
                const int n0 = (2 * wv + nt) * 16 + g * 4;
                f16x4 h;
                #pragma unroll
                for (int r = 0; r < 4; ++r) h[r] = (_Float16)fast_tanh(acc[nt][r]);
                *(f16x4*)((char*)zw + ((c * 512 + n0 * 2) ^ ((c & 7) << 4))) = h;
            }
            __syncthreads();   // writes of zw visible; also orders next iter's
                               // writes to zr after everyone's reads of zr
        } else {
            // ---- final: out = tanh(W z + x), f32x4
            #pragma unroll
            for (int nt = 0; nt < 2; ++nt) {
                const int n0 = (2 * wv + nt) * 16 + g * 4;
                f32x4 o;
                #pragma unroll
                for (int r = 0; r < 4; ++r) o[r] = fast_tanh(acc[nt][r]);
                *(f32x4*)(out + (row0 + c) * D + n0) = o;
            }
        }
    }
}

extern "C" void kernel_launch(void* const* d_in, const int* in_sizes, int n_in,
                              void* d_out, int out_size, void* d_ws, size_t ws_size,
                              hipStream_t stream) {
    const float* x = (const float*)d_in[0];   // [B, D] f32
    const float* W = (const float*)d_in[1];   // [D, D] f32
    float* out = (float*)d_out;               // [B, D] f32
    _Float16* Wh = (_Float16*)d_ws;           // 64K f16 = 128 KB frag-major W

    prep_fragpack<<<32, 256, 0, stream>>>(W, Wh);
    picard_mfma<<<B / RB, 512, 0, stream>>>(x, Wh, out);
}